// Round 10
// baseline (247.813 us; speedup 1.0000x reference)
//
#include <hip/hip_runtime.h>
#include <math.h>

#define NT     512
#define NWAVES 8
#define GB     4
#define NTOK   20
#define NTT_P  5          // token tiles for 80-row phases

typedef _Float16 f16x8 __attribute__((ext_vector_type(8)));
typedef _Float16 f16x4 __attribute__((ext_vector_type(4)));
typedef _Float16 f16x2 __attribute__((ext_vector_type(2)));
typedef float    f32x4 __attribute__((ext_vector_type(4)));

// ---- ws fp16 section: transposed, zero-padded weights W_T[n][kpad] --------
#define WS_W1A  0        // [160][32]   (N=150,K=13)
#define WS_W1B  5120     // [112][160]  (N=100,K=150)
#define WS_WA0  23040    // [112][128]  (N=100,K=100)  wa0 rows 0..99
#define WS_WA1  37376    // [112][128]
#define WS_W2A  51712    // [112][128]
#define WS_W2B  66048    // [64][128]   (N=50,K=100)
#define WS_W3A  74240    // [160][64]   (N=150,K=56)
#define WS_W3B  84480    // [112][160]  (N=100,K=150)
#define WS_W3C  102400   // [112][128]  (N=100,K=100)
#define WS_WA0H 116736   // [112][128]  wa0 rows 100..199 (g part)
#define WS_TOTAL 131072
// ---- ws f32 bias section (zero-padded), float index from ws base ----------
#define WB_BASE 65536    // = WS_TOTAL/2 (f32 units)
#define WB_B1A  0        // 160 (150)
#define WB_B1B  160      // 112 (100)
#define WB_BA0  272      // 112 (100)
#define WB_BA1  384      // 112 (100)
#define WB_B2A  496      // 112 (100)
#define WB_B2B  608      // 64  (50)
#define WB_B3A  672      // 160 (150)
#define WB_B3B  832      // 112 (100)
#define WB_B3C  944      // 112 (100)
#define WB_WA2  1056     // 112 (100)  wa2 as padded f32
#define WB_N    1168
#define PREP_TOTAL (WS_TOTAL + WB_N)

// ---- LDS arena (halves), same as R9 ---------------------------------------
#define LH_R1   0        // t1[80][168] -> s1[80][136] -> f1[80][136];
                         // tail: ha[16][168]@+0, hc[16][136]@+4096
#define LH_R2   13440    // h1[80][136] -> hb[16][136]
#define LH_R3   24320    // x[80][40] -> gq[16][136] -> s2[80][136]
                         // -> f[80][72]@+0, mv[16][72]@+8000
#define LH_HA   (LH_R1 + 0)
#define LH_HC   (LH_R1 + 4096)
#define LH_HB   (LH_R2 + 0)
#define LH_GQ   (LH_R3 + 0)
#define LH_F    (LH_R3 + 0)
#define LH_MV   (LH_R3 + 8000)
#define LF_GB   17600    // f32: gbias [4][112]
#define LF_ATT  18048    // f32: att [80]
#define LF_SS   18128    // f32: ss [24]
#define LDS_DW  18152
#define LDS_BYTES (LDS_DW * 4)   // 72608 B -> 2 blocks/CU

// ---------------------------------------------------------------------------
// prep: W_T[n][k] = (fp16) W[k][N..] zero-padded; plus zero-padded f32 biases
// ---------------------------------------------------------------------------
__device__ __forceinline__ void prep_one(const float* __restrict__ src, _Float16* dst,
                                         int local, int N, int K, int Ks)
{
    int n = local / Ks, k = local - n * Ks;
    dst[local] = (_Float16)((n < N && k < K) ? src[k * N + n] : 0.f);
}
__device__ __forceinline__ void prep_b(const float* __restrict__ src, float* dst,
                                       int idx, int N)
{
    dst[idx] = (idx < N) ? src[idx] : 0.f;
}

__global__ __launch_bounds__(256)
void prep_kernel(const float* __restrict__ w1a, const float* __restrict__ w1b,
                 const float* __restrict__ wa0, const float* __restrict__ wa1,
                 const float* __restrict__ w2a, const float* __restrict__ w2b,
                 const float* __restrict__ w3a, const float* __restrict__ w3b,
                 const float* __restrict__ w3c, const float* __restrict__ wa2,
                 const float* __restrict__ b1a, const float* __restrict__ b1b,
                 const float* __restrict__ ba0, const float* __restrict__ ba1,
                 const float* __restrict__ b2a, const float* __restrict__ b2b,
                 const float* __restrict__ b3a, const float* __restrict__ b3b,
                 const float* __restrict__ b3c,
                 _Float16* __restrict__ ws)
{
    int g = blockIdx.x * 256 + threadIdx.x;
    if (g >= PREP_TOTAL) return;
    if (g >= WS_TOTAL) {
        float* wb = (float*)ws + WB_BASE;
        int l = g - WS_TOTAL;
        if (l < WB_B1B)      prep_b(b1a, wb + WB_B1A, l - WB_B1A, 150);
        else if (l < WB_BA0) prep_b(b1b, wb + WB_B1B, l - WB_B1B, 100);
        else if (l < WB_BA1) prep_b(ba0, wb + WB_BA0, l - WB_BA0, 100);
        else if (l < WB_B2A) prep_b(ba1, wb + WB_BA1, l - WB_BA1, 100);
        else if (l < WB_B2B) prep_b(b2a, wb + WB_B2A, l - WB_B2A, 100);
        else if (l < WB_B3A) prep_b(b2b, wb + WB_B2B, l - WB_B2B, 50);
        else if (l < WB_B3B) prep_b(b3a, wb + WB_B3A, l - WB_B3A, 150);
        else if (l < WB_B3C) prep_b(b3b, wb + WB_B3B, l - WB_B3B, 100);
        else if (l < WB_WA2) prep_b(b3c, wb + WB_B3C, l - WB_B3C, 100);
        else                 prep_b(wa2, wb + WB_WA2, l - WB_WA2, 100);
        return;
    }
    if (g < WS_W1B)       prep_one(w1a, ws + WS_W1A, g - WS_W1A, 150, 13, 32);
    else if (g < WS_WA0)  prep_one(w1b, ws + WS_W1B, g - WS_W1B, 100, 150, 160);
    else if (g < WS_WA1)  prep_one(wa0, ws + WS_WA0, g - WS_WA0, 100, 100, 128);
    else if (g < WS_W2A)  prep_one(wa1, ws + WS_WA1, g - WS_WA1, 100, 100, 128);
    else if (g < WS_W2B)  prep_one(w2a, ws + WS_W2A, g - WS_W2A, 100, 100, 128);
    else if (g < WS_W3A)  prep_one(w2b, ws + WS_W2B, g - WS_W2B,  50, 100, 128);
    else if (g < WS_W3B)  prep_one(w3a, ws + WS_W3A, g - WS_W3A, 150,  56, 64);
    else if (g < WS_W3C)  prep_one(w3b, ws + WS_W3B, g - WS_W3B, 100, 150, 160);
    else if (g < WS_WA0H) prep_one(w3c, ws + WS_W3C, g - WS_W3C, 100, 100, 128);
    else                  prep_one(wa0 + 100 * 100, ws + WS_WA0H, g - WS_WA0H, 100, 100, 128);
}

// ---------------------------------------------------------------------------
// 2-D-tiled swapped-operand GEMM: item = (mt-group, nt-group).
// W-frags AND X-frags register-cached per item: X reread only MSPL times
// (was MTL), W reread NSPL times. D[feature][token]: lane (cl,kq) of tile
// (mt,nt) holds feats mt*16+kq*4+r for token nt*16+cl -> packed b64 store.
// OMODE 0: fp16 Y store. 1: f32x4 -> gbias[token][feat] (token<GB).
// BMODE 0: bias from padded f32 biasp. 1: gbias[token/20][feat..].
// SCORES: also accumulate att[token] += y . wa2p (LDS f32 atomics).
// ---------------------------------------------------------------------------
template<int KT, int MTL, int NTT, int MSPL, int NSPL,
         bool RELU, int BMODE, int OMODE, bool SCORES>
__device__ __forceinline__ void gemm2(const _Float16* X, const int Xs,
                                      const _Float16* __restrict__ WT, const int Bs,
                                      const float* __restrict__ biasp,
                                      const float* gbias,
                                      _Float16* Y, const int Ys,
                                      float* att, const float* __restrict__ wa2p,
                                      const int wv, const int lane)
{
    const int cl = lane & 15, kq = lane >> 4;
    constexpr int MG = (MTL + MSPL - 1) / MSPL;
    constexpr int NG = (NTT + NSPL - 1) / NSPL;
    constexpr int ITEMS = MSPL * NSPL;
    for (int i = wv; i < ITEMS; i += NWAVES) {
        const int img = i % MSPL, ing = i / MSPL;
        const int mt0 = img * MG, nt0 = ing * NG;
        f16x8 wf[MG][KT];
        f32x4 bv[MG];
#pragma unroll
        for (int mm = 0; mm < MG; ++mm) {
            const int mt = mt0 + mm;
            if (mt >= MTL) break;
            const _Float16* Wp = WT + (mt * 16 + cl) * Bs + kq * 8;
#pragma unroll
            for (int kt = 0; kt < KT; ++kt) wf[mm][kt] = *(const f16x8*)(Wp + kt * 32);
            if (OMODE == 1 || BMODE == 0)
                bv[mm] = *(const f32x4*)(biasp + mt * 16 + kq * 4);
        }
#pragma unroll
        for (int nn = 0; nn < NG; ++nn) {
            const int nt = nt0 + nn;
            if (nt >= NTT) break;
            const _Float16* Xp = X + (nt * 16 + cl) * Xs + kq * 8;
            f16x8 xf[KT];
#pragma unroll
            for (int kt = 0; kt < KT; ++kt) xf[kt] = *(const f16x8*)(Xp + kt * 32);
            const int token = nt * 16 + cl;
#pragma unroll
            for (int mm = 0; mm < MG; ++mm) {
                const int mt = mt0 + mm;
                if (mt >= MTL) break;
                const int fb = mt * 16 + kq * 4;
                f32x4 acc = {0.f, 0.f, 0.f, 0.f};
#pragma unroll
                for (int kt = 0; kt < KT; ++kt)
                    acc = __builtin_amdgcn_mfma_f32_16x16x32_f16(wf[mm][kt], xf[kt], acc, 0, 0, 0);
                if (OMODE == 1) {
                    if (cl < GB) {
                        f32x4 o = acc + bv[mm];
                        *(f32x4*)((float*)Y + cl * 112 + fb) = o;
                    }
                } else {
                    f32x4 bb;
                    if (BMODE == 1)
                        bb = *(const f32x4*)(gbias + (token / NTOK) * 112 + fb);
                    else
                        bb = bv[mm];
                    f32x4 y = acc + bb;
                    if (RELU) {
                        y[0] = fmaxf(y[0], 0.f); y[1] = fmaxf(y[1], 0.f);
                        y[2] = fmaxf(y[2], 0.f); y[3] = fmaxf(y[3], 0.f);
                    }
                    f16x4 o = { (_Float16)y[0], (_Float16)y[1],
                                (_Float16)y[2], (_Float16)y[3] };
                    *(f16x4*)(Y + token * Ys + fb) = o;
                    if (SCORES) {
                        if (fb < 100) {
                            f32x4 w4 = *(const f32x4*)(wa2p + fb);
                            float p = y[0] * w4[0] + y[1] * w4[1]
                                    + y[2] * w4[2] + y[3] * w4[3];
                            atomicAdd(att + token, p);
                        }
                    }
                }
            }
        }
    }
}

__global__ __launch_bounds__(NT, 4)
void vnet_kernel(const float* __restrict__ x,
                 const float* __restrict__ ba2,
                 const float* __restrict__ w3d, const float* __restrict__ b3d,
                 const _Float16* __restrict__ wsh,
                 float* __restrict__ outp)
{
    extern __shared__ float lds_f[];
    _Float16* lds_h = (_Float16*)lds_f;

    const int tid  = threadIdx.x;
    const int lane = tid & 63, wv = tid >> 6;
    const int b0   = blockIdx.x * GB;
    const float* wb = (const float*)wsh + WB_BASE;

    _Float16* xa  = lds_h + LH_R3;   // x [80][40]
    _Float16* gqh = lds_h + LH_GQ;   // [16][136] over dead x
    float* gbias = lds_f + LF_GB;
    float* att   = lds_f + LF_ATT;
    float* ss    = lds_f + LF_SS;

    // ---- P0: zero arena (all later pad-reads must be finite) -------------
    for (int i = tid; i < LDS_DW; i += NT) lds_f[i] = 0.f;
    __syncthreads();

    // ---- P1: x -> LDS row-major [token][40]; self_state ------------------
    const float* xg = x + (size_t)b0 * (NTOK * 13);
    for (int t = tid; t < GB * NTOK * 13; t += NT) {
        int row = t / 13, d = t - row * 13;
        xa[row * 40 + d] = (_Float16)xg[t];
    }
    if (tid < GB * 6) {
        int b = tid / 6, d = tid - b * 6;
        ss[tid] = xg[b * (NTOK * 13) + d];   // x[b,0,d]
    }
    __syncthreads();

    // ---- P2: t1 = relu(x @ w1a + b1a) -> R1 [80][168] --------------------
    gemm2<1, 10, NTT_P, 4, 2, true, 0, 0, false>(
        xa, 40, wsh + WS_W1A, 32, wb + WB_B1A, nullptr,
        lds_h + LH_R1, 168, nullptr, nullptr, wv, lane);
    __syncthreads();

    // ---- P3: h1 = relu(t1 @ w1b + b1b) -> R2 [80][136] -------------------
    gemm2<5, 7, NTT_P, 4, 2, true, 0, 0, false>(
        lds_h + LH_R1, 168, wsh + WS_W1B, 160, wb + WB_B1B, nullptr,
        lds_h + LH_R2, 136, nullptr, nullptr, wv, lane);
    __syncthreads();

    // ---- P4: gq (u32-pair reads) -> fp16 [16][136]; init att = ba2 -------
    const _Float16* h1 = lds_h + LH_R2;
    const uint* h1u = (const uint*)h1;
    for (int t = tid; t < GB * 50; t += NT) {
        int b = t / 50, cp = t - b * 50;
        float s0 = 0.f, s1 = 0.f;
#pragma unroll
        for (int n = 0; n < NTOK; ++n) {
            uint v = h1u[(b * NTOK + n) * 68 + cp];
            f16x2 p = *(const f16x2*)&v;
            s0 += (float)p.x; s1 += (float)p.y;
        }
        f16x2 g = { (_Float16)(s0 * 0.05f), (_Float16)(s1 * 0.05f) };
        *(f16x2*)(gqh + b * 136 + 2 * cp) = g;
    }
    if (tid < GB * NTOK) att[tid] = ba2[0];
    __syncthreads();

    // ---- P5: gbias[b][feat] = ba0[feat] + gq[b] @ wa0_hi  (f32x4 out) ----
    gemm2<4, 7, 1, 7, 1, false, 0, 1, false>(
        gqh, 136, wsh + WS_WA0H, 128, wb + WB_BA0, nullptr,
        (_Float16*)gbias, 0, nullptr, nullptr, wv, lane);
    __syncthreads();

    // ---- P6: s1 = relu(h1 @ wa0_lo + gbias) -> R1 (t1 dead) --------------
    gemm2<4, 7, NTT_P, 4, 2, true, 1, 0, false>(
        h1, 136, wsh + WS_WA0, 128, nullptr, gbias,
        lds_h + LH_R1, 136, nullptr, nullptr, wv, lane);
    __syncthreads();

    // ---- P7: s2 = relu(s1 @ wa1 + ba1) -> R3; scores fused into epilogue -
    gemm2<4, 7, NTT_P, 4, 2, true, 0, 0, true>(
        lds_h + LH_R1, 136, wsh + WS_WA1, 128, wb + WB_BA1, nullptr,
        lds_h + LH_R3, 136, att, wb + WB_WA2, wv, lane);
    __syncthreads();

    // ---- P8: f1 = relu(h1 @ w2a + b2a) -> R1 (s1 dead) -------------------
    gemm2<4, 7, NTT_P, 4, 2, true, 0, 0, false>(
        h1, 136, wsh + WS_W2A, 128, wb + WB_B2A, nullptr,
        lds_h + LH_R1, 136, nullptr, nullptr, wv, lane);
    __syncthreads();

    // ---- P9: f = f1 @ w2b + b2b -> R3 [80][72] (waves 0-3, s2 dead);
    //           softmax(att) per-b on waves 4-7 ----------------------------
    gemm2<4, 4, NTT_P, 2, 2, false, 0, 0, false>(
        lds_h + LH_R1, 136, wsh + WS_W2B, 128, wb + WB_B2B, nullptr,
        lds_h + LH_F, 72, nullptr, nullptr, wv, lane);
    if (wv >= 4 && lane == 0) {
        int b = wv - 4;
        if (b < GB) {
            float* a = att + b * NTOK;
            float mx = a[0];
#pragma unroll
            for (int n = 1; n < NTOK; ++n) mx = fmaxf(mx, a[n]);
            float s = 0.f;
#pragma unroll
            for (int n = 0; n < NTOK; ++n) { float e = expf(a[n] - mx); a[n] = e; s += e; }
            float inv = 1.f / s;
#pragma unroll
            for (int n = 0; n < NTOK; ++n) a[n] *= inv;
        }
    }
    __syncthreads();

    // ---- P10: mv[b][c] = [ss | wf] fp16 [16][72] @ R3+8000 ---------------
    _Float16* mv = lds_h + LH_MV;
    const _Float16* fh = lds_h + LH_F;
    for (int t = tid; t < GB * 56; t += NT) {
        int b = t / 56, c = t - b * 56;
        float v;
        if (c < 6) {
            v = ss[b * 6 + c];
        } else {
            int cc = c - 6;
            float acc = 0.f;
            const float* ab = att + b * NTOK;
#pragma unroll
            for (int n = 0; n < NTOK; ++n)
                acc = fmaf((float)fh[(b * NTOK + n) * 72 + cc], ab[n], acc);
            v = acc;
        }
        mv[b * 72 + c] = (_Float16)v;
    }
    __syncthreads();

    // ---- T1: ha = relu(mv @ w3a + b3a)  [16][168] @ R1 (f1 dead) ---------
    gemm2<2, 10, 1, 5, 1, true, 0, 0, false>(
        mv, 72, wsh + WS_W3A, 64, wb + WB_B3A, nullptr,
        lds_h + LH_HA, 168, nullptr, nullptr, wv, lane);
    __syncthreads();

    // ---- T2: hb = relu(ha @ w3b + b3b)  [16][136] @ R2 (h1 dead) ---------
    gemm2<5, 7, 1, 7, 1, true, 0, 0, false>(
        lds_h + LH_HA, 168, wsh + WS_W3B, 160, wb + WB_B3B, nullptr,
        lds_h + LH_HB, 136, nullptr, nullptr, wv, lane);
    __syncthreads();

    // ---- T3: hc = relu(hb @ w3c + b3c)  [16][136] @ R1+4096 --------------
    gemm2<4, 7, 1, 7, 1, true, 0, 0, false>(
        lds_h + LH_HB, 136, wsh + WS_W3C, 128, wb + WB_B3C, nullptr,
        lds_h + LH_HC, 136, nullptr, nullptr, wv, lane);
    __syncthreads();

    // ---- T4: out = hc @ w3d + b3d ----------------------------------------
    if (tid < GB) {
        const _Float16* ib = lds_h + LH_HC + tid * 136;
        float acc = b3d[0];
#pragma unroll 4
        for (int k = 0; k < 100; ++k) acc = fmaf((float)ib[k], w3d[k], acc);
        outp[b0 + tid] = acc;
    }
}

extern "C" void kernel_launch(void* const* d_in, const int* in_sizes, int n_in,
                              void* d_out, int out_size, void* d_ws, size_t ws_size,
                              hipStream_t stream)
{
    const float* x   = (const float*)d_in[0];
    const float* w1a = (const float*)d_in[1];
    const float* b1a = (const float*)d_in[2];
    const float* w1b = (const float*)d_in[3];
    const float* b1b = (const float*)d_in[4];
    const float* wa0 = (const float*)d_in[5];
    const float* ba0 = (const float*)d_in[6];
    const float* wa1 = (const float*)d_in[7];
    const float* ba1 = (const float*)d_in[8];
    const float* wa2 = (const float*)d_in[9];
    const float* ba2 = (const float*)d_in[10];
    const float* w2a = (const float*)d_in[11];
    const float* b2a = (const float*)d_in[12];
    const float* w2b = (const float*)d_in[13];
    const float* b2b = (const float*)d_in[14];
    const float* w3a = (const float*)d_in[15];
    const float* b3a = (const float*)d_in[16];
    const float* w3b = (const float*)d_in[17];
    const float* b3b = (const float*)d_in[18];
    const float* w3c = (const float*)d_in[19];
    const float* b3c = (const float*)d_in[20];
    const float* w3d = (const float*)d_in[21];
    const float* b3d = (const float*)d_in[22];
    float* outp = (float*)d_out;
    _Float16* wsh = (_Float16*)d_ws;

    hipFuncSetAttribute((const void*)vnet_kernel,
                        hipFuncAttributeMaxDynamicSharedMemorySize, LDS_BYTES);

    hipLaunchKernelGGL(prep_kernel, dim3((PREP_TOTAL + 255) / 256), dim3(256),
                       0, stream,
                       w1a, w1b, wa0, wa1, w2a, w2b, w3a, w3b, w3c, wa2,
                       b1a, b1b, ba0, ba1, b2a, b2b, b3a, b3b, b3c, wsh);

    const int B = 16384;
    hipLaunchKernelGGL(vnet_kernel, dim3(B / GB), dim3(NT), LDS_BYTES, stream,
                       x, ba2, w3d, b3d, wsh, outp);
}

// Round 11
// 179.198 us; speedup vs baseline: 1.3829x; 1.3829x over previous
//
#include <hip/hip_runtime.h>
#include <math.h>

#define NT     512
#define NWAVES 8
#define GB     4
#define NTOK   20
#define NTT_P  5          // token tiles for 80-row phases

typedef _Float16 f16x8 __attribute__((ext_vector_type(8)));
typedef _Float16 f16x4 __attribute__((ext_vector_type(4)));
typedef _Float16 f16x2 __attribute__((ext_vector_type(2)));
typedef float    f32x4 __attribute__((ext_vector_type(4)));

// ---- ws fp16 section: transposed, zero-padded weights W_T[n][kpad] --------
#define WS_W1A  0        // [160][32]   (N=150,K=13)
#define WS_W1B  5120     // [112][160]  (N=100,K=150)
#define WS_WA0  23040    // [112][128]  (N=100,K=100)  wa0 rows 0..99
#define WS_WA1  37376    // [112][128]
#define WS_W2A  51712    // [112][128]
#define WS_W2B  66048    // [64][128]   (N=50,K=100)
#define WS_W3A  74240    // [160][64]   (N=150,K=56)
#define WS_W3B  84480    // [112][160]  (N=100,K=150)
#define WS_W3C  102400   // [112][128]  (N=100,K=100)
#define WS_WA0H 116736   // [112][128]  wa0 rows 100..199 (g part)
#define WS_TOTAL 131072
// ---- ws f32 bias section (zero-padded), float index from ws base ----------
#define WB_BASE 65536    // = WS_TOTAL/2 (f32 units)
#define WB_B1A  0        // 160 (150)
#define WB_B1B  160      // 112 (100)
#define WB_BA0  272      // 112 (100)
#define WB_BA1  384      // 112 (100)
#define WB_B2A  496      // 112 (100)
#define WB_B2B  608      // 64  (50)
#define WB_B3A  672      // 160 (150)
#define WB_B3B  832      // 112 (100)
#define WB_B3C  944      // 112 (100)
#define WB_WA2  1056     // 112 (100)  wa2 as padded f32
#define WB_N    1168
#define PREP_TOTAL (WS_TOTAL + WB_N)

// ---- LDS arena (halves) ---------------------------------------------------
// R1: t1[80][168] -> f1[80][136];  tail: ha[16][168]@+0, hc[16][136]@+4096
// R2: h1[80][136] -> f[80][72] -> hb[16][136]
// R3: x[80][40] -> gq[16][136] -> s1[80][136]; mv[16][72]@+8000 (s1 dead)
#define LH_R1   0
#define LH_R2   13440
#define LH_R3   24320
#define LH_HA   (LH_R1 + 0)
#define LH_HC   (LH_R1 + 4096)
#define LH_HB   (LH_R2 + 0)
#define LH_F    (LH_R2 + 0)
#define LH_GQ   (LH_R3 + 0)
#define LH_MV   (LH_R3 + 8000)
#define LF_GB   17600    // f32: gbias [4][112]
#define LF_ATT  18048    // f32: att [80]
#define LF_SS   18128    // f32: ss [24]
#define LF_PART 18152    // f32: scores partials [80][8]
#define LDS_DW  18792
#define LDS_BYTES (LDS_DW * 4)   // 75168 B -> 2 blocks/CU

// ---------------------------------------------------------------------------
// prep: W_T[n][k] = (fp16) W[k][N..] zero-padded; plus zero-padded f32 biases
// ---------------------------------------------------------------------------
__device__ __forceinline__ void prep_one(const float* __restrict__ src, _Float16* dst,
                                         int local, int N, int K, int Ks)
{
    int n = local / Ks, k = local - n * Ks;
    dst[local] = (_Float16)((n < N && k < K) ? src[k * N + n] : 0.f);
}
__device__ __forceinline__ void prep_b(const float* __restrict__ src, float* dst,
                                       int idx, int N)
{
    dst[idx] = (idx < N) ? src[idx] : 0.f;
}

__global__ __launch_bounds__(256)
void prep_kernel(const float* __restrict__ w1a, const float* __restrict__ w1b,
                 const float* __restrict__ wa0, const float* __restrict__ wa1,
                 const float* __restrict__ w2a, const float* __restrict__ w2b,
                 const float* __restrict__ w3a, const float* __restrict__ w3b,
                 const float* __restrict__ w3c, const float* __restrict__ wa2,
                 const float* __restrict__ b1a, const float* __restrict__ b1b,
                 const float* __restrict__ ba0, const float* __restrict__ ba1,
                 const float* __restrict__ b2a, const float* __restrict__ b2b,
                 const float* __restrict__ b3a, const float* __restrict__ b3b,
                 const float* __restrict__ b3c,
                 _Float16* __restrict__ ws)
{
    int g = blockIdx.x * 256 + threadIdx.x;
    if (g >= PREP_TOTAL) return;
    if (g >= WS_TOTAL) {
        float* wb = (float*)ws + WB_BASE;
        int l = g - WS_TOTAL;
        if (l < WB_B1B)      prep_b(b1a, wb + WB_B1A, l - WB_B1A, 150);
        else if (l < WB_BA0) prep_b(b1b, wb + WB_B1B, l - WB_B1B, 100);
        else if (l < WB_BA1) prep_b(ba0, wb + WB_BA0, l - WB_BA0, 100);
        else if (l < WB_B2A) prep_b(ba1, wb + WB_BA1, l - WB_BA1, 100);
        else if (l < WB_B2B) prep_b(b2a, wb + WB_B2A, l - WB_B2A, 100);
        else if (l < WB_B3A) prep_b(b2b, wb + WB_B2B, l - WB_B2B, 50);
        else if (l < WB_B3B) prep_b(b3a, wb + WB_B3A, l - WB_B3A, 150);
        else if (l < WB_B3C) prep_b(b3b, wb + WB_B3B, l - WB_B3B, 100);
        else if (l < WB_WA2) prep_b(b3c, wb + WB_B3C, l - WB_B3C, 100);
        else                 prep_b(wa2, wb + WB_WA2, l - WB_WA2, 100);
        return;
    }
    if (g < WS_W1B)       prep_one(w1a, ws + WS_W1A, g - WS_W1A, 150, 13, 32);
    else if (g < WS_WA0)  prep_one(w1b, ws + WS_W1B, g - WS_W1B, 100, 150, 160);
    else if (g < WS_WA1)  prep_one(wa0, ws + WS_WA0, g - WS_WA0, 100, 100, 128);
    else if (g < WS_W2A)  prep_one(wa1, ws + WS_WA1, g - WS_WA1, 100, 100, 128);
    else if (g < WS_W2B)  prep_one(w2a, ws + WS_W2A, g - WS_W2A, 100, 100, 128);
    else if (g < WS_W3A)  prep_one(w2b, ws + WS_W2B, g - WS_W2B,  50, 100, 128);
    else if (g < WS_W3B)  prep_one(w3a, ws + WS_W3A, g - WS_W3A, 150,  56, 64);
    else if (g < WS_W3C)  prep_one(w3b, ws + WS_W3B, g - WS_W3B, 100, 150, 160);
    else if (g < WS_WA0H) prep_one(w3c, ws + WS_W3C, g - WS_W3C, 100, 100, 128);
    else                  prep_one(wa0 + 100 * 100, ws + WS_WA0H, g - WS_WA0H, 100, 100, 128);
}

// ---------------------------------------------------------------------------
// Swapped-operand GEMM (R9-proven schedule): item = mt; per-item W-frags
// prefetched, then nt-sweep with LDS X-reads + MFMA. D[feature][token]:
// lane (cl,kq) holds feats mt*16+kq*4+r for token nt*16+cl.
// OMODE 0: fp16 Y[token][feat] packed b64 store.
// OMODE 1: f32x4 -> gbias[token][feat] (token<GB).
// OMODE 2: scores-partial: y=relu(s2); p = y . wa2p[fb..]; kq-reduce via
//          shfl_xor(16/32); kq==0 stores part[token*8+mt]. No Y store.
// BMODE 0: bias from padded f32 biasp. 1: gbias[token/20][feat..].
// ---------------------------------------------------------------------------
template<int KT, int MTL, int NTT, bool RELU, int BMODE, int OMODE>
__device__ __forceinline__ void gemm_sw(const _Float16* X, const int Xs,
                                        const _Float16* __restrict__ WT, const int Bs,
                                        const float* __restrict__ biasp,
                                        const float* gbias,
                                        _Float16* Y, const int Ys,
                                        float* part, const float* __restrict__ wa2p,
                                        const int wv, const int lane)
{
    const int cl = lane & 15, kq = lane >> 4;
    constexpr int IPW = (MTL + NWAVES - 1) / NWAVES;
    f16x8 wf[IPW][KT];
    f32x4 bv[IPW];
#pragma unroll
    for (int ii = 0; ii < IPW; ++ii) {
        const int mt = wv + ii * NWAVES;
        if (mt < MTL) {
            const _Float16* Wp = WT + (mt * 16 + cl) * Bs + kq * 8;
#pragma unroll
            for (int kt = 0; kt < KT; ++kt) wf[ii][kt] = *(const f16x8*)(Wp + kt * 32);
            if (BMODE == 0)
                bv[ii] = *(const f32x4*)(biasp + mt * 16 + kq * 4);
        }
    }
#pragma unroll
    for (int ii = 0; ii < IPW; ++ii) {
        const int mt = wv + ii * NWAVES;
        if (mt >= MTL) break;
        const int fb = mt * 16 + kq * 4;
#pragma unroll
        for (int nt = 0; nt < NTT; ++nt) {
            const _Float16* Xp = X + (nt * 16 + cl) * Xs + kq * 8;
            f16x8 xf[KT];
#pragma unroll
            for (int kt = 0; kt < KT; ++kt) xf[kt] = *(const f16x8*)(Xp + kt * 32);
            f32x4 acc = {0.f, 0.f, 0.f, 0.f};
#pragma unroll
            for (int kt = 0; kt < KT; ++kt)
                acc = __builtin_amdgcn_mfma_f32_16x16x32_f16(wf[ii][kt], xf[kt], acc, 0, 0, 0);
            const int token = nt * 16 + cl;
            if (OMODE == 1) {
                if (cl < GB) {
                    f32x4 o = acc + bv[ii];
                    *(f32x4*)((float*)Y + cl * 112 + fb) = o;
                }
            } else if (OMODE == 2) {
                f32x4 y = acc + bv[ii];
                y[0] = fmaxf(y[0], 0.f); y[1] = fmaxf(y[1], 0.f);
                y[2] = fmaxf(y[2], 0.f); y[3] = fmaxf(y[3], 0.f);
                f32x4 w4 = *(const f32x4*)(wa2p + fb);
                float p = y[0] * w4[0] + y[1] * w4[1] + y[2] * w4[2] + y[3] * w4[3];
                p += __shfl_xor(p, 16);
                p += __shfl_xor(p, 32);
                if (kq == 0) part[token * 8 + mt] = p;
            } else {
                f32x4 bb;
                if (BMODE == 1)
                    bb = *(const f32x4*)(gbias + (token / NTOK) * 112 + fb);
                else
                    bb = bv[ii];
                f32x4 y = acc + bb;
                if (RELU) {
                    y[0] = fmaxf(y[0], 0.f); y[1] = fmaxf(y[1], 0.f);
                    y[2] = fmaxf(y[2], 0.f); y[3] = fmaxf(y[3], 0.f);
                }
                f16x4 o = { (_Float16)y[0], (_Float16)y[1],
                            (_Float16)y[2], (_Float16)y[3] };
                *(f16x4*)(Y + token * Ys + fb) = o;
            }
        }
    }
}

__global__ __launch_bounds__(NT, 4)
void vnet_kernel(const float* __restrict__ x,
                 const float* __restrict__ ba2,
                 const float* __restrict__ w3d, const float* __restrict__ b3d,
                 const _Float16* __restrict__ wsh,
                 float* __restrict__ outp)
{
    extern __shared__ float lds_f[];
    _Float16* lds_h = (_Float16*)lds_f;

    const int tid  = threadIdx.x;
    const int lane = tid & 63, wv = tid >> 6;
    const int b0   = blockIdx.x * GB;
    const float* wb = (const float*)wsh + WB_BASE;

    _Float16* xa  = lds_h + LH_R3;   // x [80][40]
    _Float16* gqh = lds_h + LH_GQ;   // [16][136] over dead x
    float* gbias = lds_f + LF_GB;
    float* att   = lds_f + LF_ATT;
    float* ss    = lds_f + LF_SS;
    float* part  = lds_f + LF_PART;

    // ---- P0: zero arena (all later pad-reads must be finite) -------------
    for (int i = tid; i < LDS_DW; i += NT) lds_f[i] = 0.f;
    __syncthreads();

    // ---- P1: x -> LDS row-major [token][40]; self_state ------------------
    const float* xg = x + (size_t)b0 * (NTOK * 13);
    for (int t = tid; t < GB * NTOK * 13; t += NT) {
        int row = t / 13, d = t - row * 13;
        xa[row * 40 + d] = (_Float16)xg[t];
    }
    if (tid < GB * 6) {
        int b = tid / 6, d = tid - b * 6;
        ss[tid] = xg[b * (NTOK * 13) + d];   // x[b,0,d]
    }
    __syncthreads();

    // ---- P2: t1 = relu(x @ w1a + b1a) -> R1 [80][168] --------------------
    gemm_sw<1, 10, NTT_P, true, 0, 0>(xa, 40, wsh + WS_W1A, 32, wb + WB_B1A,
                                      nullptr, lds_h + LH_R1, 168,
                                      nullptr, nullptr, wv, lane);
    __syncthreads();

    // ---- P3: h1 = relu(t1 @ w1b + b1b) -> R2 [80][136] -------------------
    gemm_sw<5, 7, NTT_P, true, 0, 0>(lds_h + LH_R1, 168, wsh + WS_W1B, 160,
                                     wb + WB_B1B, nullptr, lds_h + LH_R2, 136,
                                     nullptr, nullptr, wv, lane);
    __syncthreads();

    // ---- P4: gq[b][c] = mean_n h1 (u32-paired) -> fp16 [16][136] ---------
    const _Float16* h1 = lds_h + LH_R2;
    const uint* h1u = (const uint*)h1;
    for (int t = tid; t < GB * 50; t += NT) {
        int b = t / 50, cp = t - b * 50;
        float s0 = 0.f, s1 = 0.f;
#pragma unroll
        for (int n = 0; n < NTOK; ++n) {
            uint v = h1u[(b * NTOK + n) * 68 + cp];
            f16x2 p = *(const f16x2*)&v;
            s0 += (float)p.x; s1 += (float)p.y;
        }
        f16x2 g = { (_Float16)(s0 * 0.05f), (_Float16)(s1 * 0.05f) };
        *(f16x2*)(gqh + b * 136 + 2 * cp) = g;
    }
    __syncthreads();

    // ---- M1: gbias (waves 1-7) + f1 = relu(h1@w2a+b2a) -> R1 (waves 0-6) -
    gemm_sw<4, 7, 1, false, 0, 1>(gqh, 136, wsh + WS_WA0H, 128, wb + WB_BA0,
                                  nullptr, (_Float16*)gbias, 0,
                                  nullptr, nullptr, (NWAVES - 1) - wv, lane);
    gemm_sw<4, 7, NTT_P, true, 0, 0>(h1, 136, wsh + WS_W2A, 128, wb + WB_B2A,
                                     nullptr, lds_h + LH_R1, 136,
                                     nullptr, nullptr, wv, lane);
    __syncthreads();

    // ---- M2: s1 = relu(h1 @ wa0_lo + gbias) -> R3 (x/gq dead) ------------
    gemm_sw<4, 7, NTT_P, true, 1, 0>(h1, 136, wsh + WS_WA0, 128, nullptr,
                                     gbias, lds_h + LH_R3, 136,
                                     nullptr, nullptr, wv, lane);
    __syncthreads();

    // ---- M3: s2-scores partials (waves 0-6, no s2 store) +
    //          f = f1 @ w2b + b2b -> R2 head [80][72] (waves 7-4; h1 dead) --
    gemm_sw<4, 7, NTT_P, true, 0, 2>(lds_h + LH_R3, 136, wsh + WS_WA1, 128,
                                     wb + WB_BA1, nullptr, nullptr, 0,
                                     part, wb + WB_WA2, wv, lane);
    gemm_sw<4, 4, NTT_P, false, 0, 0>(lds_h + LH_R1, 136, wsh + WS_W2B, 128,
                                      wb + WB_B2B, nullptr, lds_h + LH_F, 72,
                                      nullptr, nullptr, (NWAVES - 1) - wv, lane);
    __syncthreads();

    // ---- M4a: att[token] = ba2 + sum_mt part ------------------------------
    if (tid < GB * NTOK) {
        float r = ba2[0];
#pragma unroll
        for (int m = 0; m < 7; ++m) r += part[tid * 8 + m];
        att[tid] = r;
    }
    __syncthreads();

    // ---- M4b: softmax per b (waves 4-7, lane 0) ---------------------------
    if (wv >= 4 && lane == 0) {
        int b = wv - 4;
        if (b < GB) {
            float* a = att + b * NTOK;
            float mx = a[0];
#pragma unroll
            for (int n = 1; n < NTOK; ++n) mx = fmaxf(mx, a[n]);
            float s = 0.f;
#pragma unroll
            for (int n = 0; n < NTOK; ++n) { float e = expf(a[n] - mx); a[n] = e; s += e; }
            float inv = 1.f / s;
#pragma unroll
            for (int n = 0; n < NTOK; ++n) a[n] *= inv;
        }
    }
    __syncthreads();

    // ---- P10: mv[b][c] = [ss | wf] fp16 [16][72] @ R3+8000 (s1 dead) -----
    _Float16* mv = lds_h + LH_MV;
    const _Float16* fh = lds_h + LH_F;
    for (int t = tid; t < GB * 56; t += NT) {
        int b = t / 56, c = t - b * 56;
        float v;
        if (c < 6) {
            v = ss[b * 6 + c];
        } else {
            int cc = c - 6;
            float acc = 0.f;
            const float* ab = att + b * NTOK;
#pragma unroll
            for (int n = 0; n < NTOK; ++n)
                acc = fmaf((float)fh[(b * NTOK + n) * 72 + cc], ab[n], acc);
            v = acc;
        }
        mv[b * 72 + c] = (_Float16)v;
    }
    __syncthreads();

    // ---- T1: ha = relu(mv @ w3a + b3a)  [16][168] @ R1 (f1 dead) ---------
    gemm_sw<2, 10, 1, true, 0, 0>(mv, 72, wsh + WS_W3A, 64, wb + WB_B3A,
                                  nullptr, lds_h + LH_HA, 168,
                                  nullptr, nullptr, wv, lane);
    __syncthreads();

    // ---- T2: hb = relu(ha @ w3b + b3b)  [16][136] @ R2 (f dead) ----------
    gemm_sw<5, 7, 1, true, 0, 0>(lds_h + LH_HA, 168, wsh + WS_W3B, 160,
                                 wb + WB_B3B, nullptr, lds_h + LH_HB, 136,
                                 nullptr, nullptr, wv, lane);
    __syncthreads();

    // ---- T3: hc = relu(hb @ w3c + b3c)  [16][136] @ R1+4096 --------------
    gemm_sw<4, 7, 1, true, 0, 0>(lds_h + LH_HB, 136, wsh + WS_W3C, 128,
                                 wb + WB_B3C, nullptr, lds_h + LH_HC, 136,
                                 nullptr, nullptr, wv, lane);
    __syncthreads();

    // ---- T4: out = hc @ w3d + b3d ----------------------------------------
    if (tid < GB) {
        const _Float16* ib = lds_h + LH_HC + tid * 136;
        float acc = b3d[0];
#pragma unroll 4
        for (int k = 0; k < 100; ++k) acc = fmaf((float)ib[k], w3d[k], acc);
        outp[b0 + tid] = acc;
    }
}

extern "C" void kernel_launch(void* const* d_in, const int* in_sizes, int n_in,
                              void* d_out, int out_size, void* d_ws, size_t ws_size,
                              hipStream_t stream)
{
    const float* x   = (const float*)d_in[0];
    const float* w1a = (const float*)d_in[1];
    const float* b1a = (const float*)d_in[2];
    const float* w1b = (const float*)d_in[3];
    const float* b1b = (const float*)d_in[4];
    const float* wa0 = (const float*)d_in[5];
    const float* ba0 = (const float*)d_in[6];
    const float* wa1 = (const float*)d_in[7];
    const float* ba1 = (const float*)d_in[8];
    const float* wa2 = (const float*)d_in[9];
    const float* ba2 = (const float*)d_in[10];
    const float* w2a = (const float*)d_in[11];
    const float* b2a = (const float*)d_in[12];
    const float* w2b = (const float*)d_in[13];
    const float* b2b = (const float*)d_in[14];
    const float* w3a = (const float*)d_in[15];
    const float* b3a = (const float*)d_in[16];
    const float* w3b = (const float*)d_in[17];
    const float* b3b = (const float*)d_in[18];
    const float* w3c = (const float*)d_in[19];
    const float* b3c = (const float*)d_in[20];
    const float* w3d = (const float*)d_in[21];
    const float* b3d = (const float*)d_in[22];
    float* outp = (float*)d_out;
    _Float16* wsh = (_Float16*)d_ws;

    hipFuncSetAttribute((const void*)vnet_kernel,
                        hipFuncAttributeMaxDynamicSharedMemorySize, LDS_BYTES);

    hipLaunchKernelGGL(prep_kernel, dim3((PREP_TOTAL + 255) / 256), dim3(256),
                       0, stream,
                       w1a, w1b, wa0, wa1, w2a, w2b, w3a, w3b, w3c, wa2,
                       b1a, b1b, ba0, ba1, b2a, b2b, b3a, b3b, b3c, wsh);

    const int B = 16384;
    hipLaunchKernelGGL(vnet_kernel, dim3(B / GB), dim3(NT), LDS_BYTES, stream,
                       x, ba2, w3d, b3d, wsh, outp);
}

// Round 12
// 144.348 us; speedup vs baseline: 1.7168x; 1.2414x over previous
//
#include <hip/hip_runtime.h>
#include <math.h>

#define NT     512
#define NWAVES 8
#define GB     4
#define NTOK   20
#define NTT_P  5          // token tiles for 80-row phases

typedef _Float16 f16x8 __attribute__((ext_vector_type(8)));
typedef _Float16 f16x4 __attribute__((ext_vector_type(4)));
typedef _Float16 f16x2 __attribute__((ext_vector_type(2)));
typedef float    f32x4 __attribute__((ext_vector_type(4)));

// ---- ws fp16 section: transposed, zero-padded weights W_T[n][kpad] --------
#define WS_W1A  0        // [160][32]   (N=150,K=13)
#define WS_W1B  5120     // [112][160]  (N=100,K=150)
#define WS_WA0  23040    // [112][128]  (N=100,K=100)  wa0 rows 0..99
#define WS_WA1  37376    // [112][128]
#define WS_W2A  51712    // [112][128]
#define WS_W2B  66048    // [64][128]   (N=50,K=100)
#define WS_W3A  74240    // [160][64]   (N=150,K=56)
#define WS_W3B  84480    // [112][160]  (N=100,K=150)
#define WS_W3C  102400   // [112][128]  (N=100,K=100)
#define WS_WA0H 116736   // [112][128]  wa0 rows 100..199 (g part)
#define WS_TOTAL 131072
// ---- ws f32 bias section (zero-padded), float index from ws base ----------
#define WB_BASE 65536    // = WS_TOTAL/2 (f32 units)
#define WB_B1A  0
#define WB_B1B  160
#define WB_BA0  272
#define WB_BA1  384
#define WB_B2A  496
#define WB_B2B  608
#define WB_B3A  672
#define WB_B3B  832
#define WB_B3C  944
#define WB_WA2  1056
#define WB_N    1168
#define PREP_TOTAL (WS_TOTAL + WB_N)

// ---- LDS arena (halves), 51.7 KB -> 3 blocks/CU ---------------------------
// A [0,12160)    : t1[80][152] (CLW=152) -> s1[80][136] -> f1[80][136]
//                  tail reuse: mv[16][72]@0 -> hc[16][136]@0
// B [12160,23040): h1[80][136] -> f[80][72] -> hb[16][136]
// C [23040,26240): x[80][40] -> gq[16][136] / gbias(f32@+2304) ->
//                  part(f32@+0) -> ha[16][168]
#define LH_A    0
#define LH_B    12160
#define LH_C    23040
#define LH_T1   LH_A          // stride 152
#define LH_S1   LH_A          // stride 136
#define LH_F1   LH_A          // stride 136
#define LH_MV   LH_A          // [16][72]
#define LH_HC   LH_A          // [16][136]
#define LH_H1   LH_B          // stride 136
#define LH_FF   LH_B          // [80][72]
#define LH_HB   LH_B          // [16][136]
#define LH_X    LH_C          // stride 40
#define LH_GQ   LH_C          // [16][136]
#define LH_HA   LH_C          // [16][168]
#define LF_PART 11520         // f32: part [80][8]  (= LH_C/2)
#define LF_GB   12672         // f32: gbias [4][112] (= (LH_C+2304)/2)
#define LF_ATT  13120         // f32: att [80]
#define LF_SS   13200         // f32: ss [24]
#define LDS_DW  13224
#define LDS_BYTES (LDS_DW * 4)   // 52896 B

// ---------------------------------------------------------------------------
// prep: W_T[n][k] = (fp16) W[k][N..] zero-padded; plus zero-padded f32 biases
// ---------------------------------------------------------------------------
__device__ __forceinline__ void prep_one(const float* __restrict__ src, _Float16* dst,
                                         int local, int N, int K, int Ks)
{
    int n = local / Ks, k = local - n * Ks;
    dst[local] = (_Float16)((n < N && k < K) ? src[k * N + n] : 0.f);
}
__device__ __forceinline__ void prep_b(const float* __restrict__ src, float* dst,
                                       int idx, int N)
{
    dst[idx] = (idx < N) ? src[idx] : 0.f;
}

__global__ __launch_bounds__(256)
void prep_kernel(const float* __restrict__ w1a, const float* __restrict__ w1b,
                 const float* __restrict__ wa0, const float* __restrict__ wa1,
                 const float* __restrict__ w2a, const float* __restrict__ w2b,
                 const float* __restrict__ w3a, const float* __restrict__ w3b,
                 const float* __restrict__ w3c, const float* __restrict__ wa2,
                 const float* __restrict__ b1a, const float* __restrict__ b1b,
                 const float* __restrict__ ba0, const float* __restrict__ ba1,
                 const float* __restrict__ b2a, const float* __restrict__ b2b,
                 const float* __restrict__ b3a, const float* __restrict__ b3b,
                 const float* __restrict__ b3c,
                 _Float16* __restrict__ ws)
{
    int g = blockIdx.x * 256 + threadIdx.x;
    if (g >= PREP_TOTAL) return;
    if (g >= WS_TOTAL) {
        float* wb = (float*)ws + WB_BASE;
        int l = g - WS_TOTAL;
        if (l < WB_B1B)      prep_b(b1a, wb + WB_B1A, l - WB_B1A, 150);
        else if (l < WB_BA0) prep_b(b1b, wb + WB_B1B, l - WB_B1B, 100);
        else if (l < WB_BA1) prep_b(ba0, wb + WB_BA0, l - WB_BA0, 100);
        else if (l < WB_B2A) prep_b(ba1, wb + WB_BA1, l - WB_BA1, 100);
        else if (l < WB_B2B) prep_b(b2a, wb + WB_B2A, l - WB_B2A, 100);
        else if (l < WB_B3A) prep_b(b2b, wb + WB_B2B, l - WB_B2B, 50);
        else if (l < WB_B3B) prep_b(b3a, wb + WB_B3A, l - WB_B3A, 150);
        else if (l < WB_B3C) prep_b(b3b, wb + WB_B3B, l - WB_B3B, 100);
        else if (l < WB_WA2) prep_b(b3c, wb + WB_B3C, l - WB_B3C, 100);
        else                 prep_b(wa2, wb + WB_WA2, l - WB_WA2, 100);
        return;
    }
    if (g < WS_W1B)       prep_one(w1a, ws + WS_W1A, g - WS_W1A, 150, 13, 32);
    else if (g < WS_WA0)  prep_one(w1b, ws + WS_W1B, g - WS_W1B, 100, 150, 160);
    else if (g < WS_WA1)  prep_one(wa0, ws + WS_WA0, g - WS_WA0, 100, 100, 128);
    else if (g < WS_W2A)  prep_one(wa1, ws + WS_WA1, g - WS_WA1, 100, 100, 128);
    else if (g < WS_W2B)  prep_one(w2a, ws + WS_W2A, g - WS_W2A, 100, 100, 128);
    else if (g < WS_W3A)  prep_one(w2b, ws + WS_W2B, g - WS_W2B,  50, 100, 128);
    else if (g < WS_W3B)  prep_one(w3a, ws + WS_W3A, g - WS_W3A, 150,  56, 64);
    else if (g < WS_W3C)  prep_one(w3b, ws + WS_W3B, g - WS_W3B, 100, 150, 160);
    else if (g < WS_WA0H) prep_one(w3c, ws + WS_W3C, g - WS_W3C, 100, 100, 128);
    else                  prep_one(wa0 + 100 * 100, ws + WS_WA0H, g - WS_WA0H, 100, 100, 128);
}

// ---------------------------------------------------------------------------
// Swapped-operand GEMM (R9 schedule): item = mt; W-frags prefetched, nt-sweep
// with LDS X-reads + MFMA. D[feature][token]; lane (cl,kq) holds feats
// mt*16+kq*4+r for token nt*16+cl.
// OMODE 0: fp16 Y[token][feat] b64 store, clamped to fb<CLW.
// OMODE 1: f32x4 -> gbias[token][feat] (token<GB).
// OMODE 2: scores-partial: y=relu(s2); p=y.wa2p; kq-reduce shfl_xor(16/32);
//          kq==0 stores part[token*8+mt].
// BMODE 0: bias from padded f32 biasp. 1: gbias[token/20][feat..].
// ---------------------------------------------------------------------------
template<int KT, int MTL, int NTT, bool RELU, int BMODE, int OMODE, int CLW>
__device__ __forceinline__ void gemm_sw(const _Float16* X, const int Xs,
                                        const _Float16* __restrict__ WT, const int Bs,
                                        const float* __restrict__ biasp,
                                        const float* gbias,
                                        _Float16* Y, const int Ys,
                                        float* part, const float* __restrict__ wa2p,
                                        const int wv, const int lane)
{
    const int cl = lane & 15, kq = lane >> 4;
    constexpr int IPW = (MTL + NWAVES - 1) / NWAVES;
    f16x8 wf[IPW][KT];
    f32x4 bv[IPW];
#pragma unroll
    for (int ii = 0; ii < IPW; ++ii) {
        const int mt = wv + ii * NWAVES;
        if (mt < MTL) {
            const _Float16* Wp = WT + (mt * 16 + cl) * Bs + kq * 8;
#pragma unroll
            for (int kt = 0; kt < KT; ++kt) wf[ii][kt] = *(const f16x8*)(Wp + kt * 32);
            if (BMODE == 0)
                bv[ii] = *(const f32x4*)(biasp + mt * 16 + kq * 4);
        }
    }
#pragma unroll
    for (int ii = 0; ii < IPW; ++ii) {
        const int mt = wv + ii * NWAVES;
        if (mt >= MTL) break;
        const int fb = mt * 16 + kq * 4;
#pragma unroll
        for (int nt = 0; nt < NTT; ++nt) {
            const _Float16* Xp = X + (nt * 16 + cl) * Xs + kq * 8;
            f16x8 xf[KT];
#pragma unroll
            for (int kt = 0; kt < KT; ++kt) xf[kt] = *(const f16x8*)(Xp + kt * 32);
            f32x4 acc = {0.f, 0.f, 0.f, 0.f};
#pragma unroll
            for (int kt = 0; kt < KT; ++kt)
                acc = __builtin_amdgcn_mfma_f32_16x16x32_f16(wf[ii][kt], xf[kt], acc, 0, 0, 0);
            const int token = nt * 16 + cl;
            if (OMODE == 1) {
                if (cl < GB) {
                    f32x4 o = acc + bv[ii];
                    *(f32x4*)((float*)Y + cl * 112 + fb) = o;
                }
            } else if (OMODE == 2) {
                f32x4 y = acc + bv[ii];
                y[0] = fmaxf(y[0], 0.f); y[1] = fmaxf(y[1], 0.f);
                y[2] = fmaxf(y[2], 0.f); y[3] = fmaxf(y[3], 0.f);
                f32x4 w4 = *(const f32x4*)(wa2p + fb);
                float p = y[0] * w4[0] + y[1] * w4[1] + y[2] * w4[2] + y[3] * w4[3];
                p += __shfl_xor(p, 16);
                p += __shfl_xor(p, 32);
                if (kq == 0) part[token * 8 + mt] = p;
            } else {
                f32x4 bb;
                if (BMODE == 1)
                    bb = *(const f32x4*)(gbias + (token / NTOK) * 112 + fb);
                else
                    bb = bv[ii];
                f32x4 y = acc + bb;
                if (RELU) {
                    y[0] = fmaxf(y[0], 0.f); y[1] = fmaxf(y[1], 0.f);
                    y[2] = fmaxf(y[2], 0.f); y[3] = fmaxf(y[3], 0.f);
                }
                if (fb < CLW) {
                    f16x4 o = { (_Float16)y[0], (_Float16)y[1],
                                (_Float16)y[2], (_Float16)y[3] };
                    *(f16x4*)(Y + token * Ys + fb) = o;
                }
            }
        }
    }
}

__global__ __launch_bounds__(NT, 6)
void vnet_kernel(const float* __restrict__ x,
                 const float* __restrict__ ba2,
                 const float* __restrict__ w3d, const float* __restrict__ b3d,
                 const _Float16* __restrict__ wsh,
                 float* __restrict__ outp)
{
    extern __shared__ float lds_f[];
    _Float16* lds_h = (_Float16*)lds_f;

    const int tid  = threadIdx.x;
    const int lane = tid & 63, wv = tid >> 6;
    const int b0   = blockIdx.x * GB;
    const float* wb = (const float*)wsh + WB_BASE;

    _Float16* xa  = lds_h + LH_X;
    _Float16* gqh = lds_h + LH_GQ;
    float* gbias = lds_f + LF_GB;
    float* att   = lds_f + LF_ATT;
    float* ss    = lds_f + LF_SS;
    float* part  = lds_f + LF_PART;

    // ---- P0: zero arena (finite/zero base for all pad & overflow reads) --
    for (int i = tid; i < LDS_DW; i += NT) lds_f[i] = 0.f;
    __syncthreads();

    // ---- P1: x -> C row-major [token][40]; self_state --------------------
    const float* xg = x + (size_t)b0 * (NTOK * 13);
    for (int t = tid; t < GB * NTOK * 13; t += NT) {
        int row = t / 13, d = t - row * 13;
        xa[row * 40 + d] = (_Float16)xg[t];
    }
    if (tid < GB * 6) {
        int b = tid / 6, d = tid - b * 6;
        ss[tid] = xg[b * (NTOK * 13) + d];   // x[b,0,d]
    }
    __syncthreads();

    // ---- P2: t1 = relu(x @ w1a + b1a) -> A [80][152], stores fb<152 ------
    gemm_sw<1, 10, NTT_P, true, 0, 0, 152>(xa, 40, wsh + WS_W1A, 32, wb + WB_B1A,
                                           nullptr, lds_h + LH_T1, 152,
                                           nullptr, nullptr, wv, lane);
    __syncthreads();

    // ---- P3: h1 = relu(t1 @ w1b + b1b) -> B [80][136] --------------------
    // (KT=5 reads t1 halves 152..159 past row end: finite x W1B-zero rows)
    gemm_sw<5, 7, NTT_P, true, 0, 0, 10000>(lds_h + LH_T1, 152, wsh + WS_W1B, 160,
                                            wb + WB_B1B, nullptr, lds_h + LH_H1, 136,
                                            nullptr, nullptr, wv, lane);
    __syncthreads();

    // ---- P4: gq[b][c] = mean_n h1 (u32-paired) -> fp16 [16][136] @ C -----
    const _Float16* h1 = lds_h + LH_H1;
    const uint* h1u = (const uint*)h1;
    for (int t = tid; t < GB * 50; t += NT) {
        int b = t / 50, cp = t - b * 50;
        float s0 = 0.f, s1 = 0.f;
#pragma unroll
        for (int n = 0; n < NTOK; ++n) {
            uint v = h1u[(b * NTOK + n) * 68 + cp];
            f16x2 p = *(const f16x2*)&v;
            s0 += (float)p.x; s1 += (float)p.y;
        }
        f16x2 g = { (_Float16)(s0 * 0.05f), (_Float16)(s1 * 0.05f) };
        *(f16x2*)(gqh + b * 136 + 2 * cp) = g;
    }
    __syncthreads();

    // ---- Mg: gbias = ba0 + gq @ wa0_hi (f32 out @ C+2304) ----------------
    gemm_sw<4, 7, 1, false, 0, 1, 10000>(gqh, 136, wsh + WS_WA0H, 128, wb + WB_BA0,
                                         nullptr, (_Float16*)gbias, 0,
                                         nullptr, nullptr, wv, lane);
    __syncthreads();

    // ---- M1: s1 = relu(h1 @ wa0_lo + gbias) -> A (t1 dead) ---------------
    gemm_sw<4, 7, NTT_P, true, 1, 0, 10000>(h1, 136, wsh + WS_WA0, 128, nullptr,
                                            gbias, lds_h + LH_S1, 136,
                                            nullptr, nullptr, wv, lane);
    __syncthreads();

    // ---- M2: s2-scores partials from s1 (no s2 store) -> part (C, gq dead)
    gemm_sw<4, 7, NTT_P, true, 0, 2, 10000>(lds_h + LH_S1, 136, wsh + WS_WA1, 128,
                                            wb + WB_BA1, nullptr, nullptr, 0,
                                            part, wb + WB_WA2, wv, lane);
    __syncthreads();

    // ---- M3: f1 = relu(h1 @ w2a + b2a) -> A (s1 dead) --------------------
    gemm_sw<4, 7, NTT_P, true, 0, 0, 10000>(h1, 136, wsh + WS_W2A, 128, wb + WB_B2A,
                                            nullptr, lds_h + LH_F1, 136,
                                            nullptr, nullptr, wv, lane);
    __syncthreads();

    // ---- M4: f = f1 @ w2b + b2b -> B head [80][72] (waves 0-3, h1 dead);
    //          att-sum + softmax wave-synchronous on waves 4-7 -------------
    gemm_sw<4, 4, NTT_P, false, 0, 0, 10000>(lds_h + LH_F1, 136, wsh + WS_W2B, 128,
                                             wb + WB_B2B, nullptr, lds_h + LH_FF, 72,
                                             nullptr, nullptr, wv, lane);
    if (wv >= 4) {
        int b = wv - 4;
        float sc = -1e30f;
        if (lane < NTOK) {
            sc = ba2[0];
            const float* pr = part + (b * NTOK + lane) * 8;
#pragma unroll
            for (int m = 0; m < 7; ++m) sc += pr[m];
        }
        float mx = sc;
#pragma unroll
        for (int off = 16; off; off >>= 1) mx = fmaxf(mx, __shfl_xor(mx, off, 32));
        float e = (lane < NTOK) ? expf(sc - mx) : 0.f;
        float s = e;
#pragma unroll
        for (int off = 16; off; off >>= 1) s += __shfl_xor(s, off, 32);
        if (lane < NTOK) att[b * NTOK + lane] = e / s;
    }
    __syncthreads();

    // ---- P10: mv[b][c] = [ss | wf] fp16 [16][72] -> A head (f1 dead) -----
    _Float16* mv = lds_h + LH_MV;
    const _Float16* fh = lds_h + LH_FF;
    for (int t = tid; t < GB * 56; t += NT) {
        int b = t / 56, c = t - b * 56;
        float v;
        if (c < 6) {
            v = ss[b * 6 + c];
        } else {
            int cc = c - 6;
            float acc = 0.f;
            const float* ab = att + b * NTOK;
#pragma unroll
            for (int n = 0; n < NTOK; ++n)
                acc = fmaf((float)fh[(b * NTOK + n) * 72 + cc], ab[n], acc);
            v = acc;
        }
        mv[b * 72 + c] = (_Float16)v;
    }
    __syncthreads();

    // ---- T1: ha = relu(mv @ w3a + b3a) [16][168] -> C (part/gbias dead) --
    gemm_sw<2, 10, 1, true, 0, 0, 10000>(mv, 72, wsh + WS_W3A, 64, wb + WB_B3A,
                                         nullptr, lds_h + LH_HA, 168,
                                         nullptr, nullptr, wv, lane);
    __syncthreads();

    // ---- T2: hb = relu(ha @ w3b + b3b) [16][136] -> B head (f dead) ------
    gemm_sw<5, 7, 1, true, 0, 0, 10000>(lds_h + LH_HA, 168, wsh + WS_W3B, 160,
                                        wb + WB_B3B, nullptr, lds_h + LH_HB, 136,
                                        nullptr, nullptr, wv, lane);
    __syncthreads();

    // ---- T3: hc = relu(hb @ w3c + b3c) [16][136] -> A head (mv dead) -----
    gemm_sw<4, 7, 1, true, 0, 0, 10000>(lds_h + LH_HB, 136, wsh + WS_W3C, 128,
                                        wb + WB_B3C, nullptr, lds_h + LH_HC, 136,
                                        nullptr, nullptr, wv, lane);
    __syncthreads();

    // ---- T4: out = hc @ w3d + b3d ----------------------------------------
    if (tid < GB) {
        const _Float16* ib = lds_h + LH_HC + tid * 136;
        float acc = b3d[0];
#pragma unroll 4
        for (int k = 0; k < 100; ++k) acc = fmaf((float)ib[k], w3d[k], acc);
        outp[b0 + tid] = acc;
    }
}

extern "C" void kernel_launch(void* const* d_in, const int* in_sizes, int n_in,
                              void* d_out, int out_size, void* d_ws, size_t ws_size,
                              hipStream_t stream)
{
    const float* x   = (const float*)d_in[0];
    const float* w1a = (const float*)d_in[1];
    const float* b1a = (const float*)d_in[2];
    const float* w1b = (const float*)d_in[3];
    const float* b1b = (const float*)d_in[4];
    const float* wa0 = (const float*)d_in[5];
    const float* ba0 = (const float*)d_in[6];
    const float* wa1 = (const float*)d_in[7];
    const float* ba1 = (const float*)d_in[8];
    const float* wa2 = (const float*)d_in[9];
    const float* ba2 = (const float*)d_in[10];
    const float* w2a = (const float*)d_in[11];
    const float* b2a = (const float*)d_in[12];
    const float* w2b = (const float*)d_in[13];
    const float* b2b = (const float*)d_in[14];
    const float* w3a = (const float*)d_in[15];
    const float* b3a = (const float*)d_in[16];
    const float* w3b = (const float*)d_in[17];
    const float* b3b = (const float*)d_in[18];
    const float* w3c = (const float*)d_in[19];
    const float* b3c = (const float*)d_in[20];
    const float* w3d = (const float*)d_in[21];
    const float* b3d = (const float*)d_in[22];
    float* outp = (float*)d_out;
    _Float16* wsh = (_Float16*)d_ws;

    hipFuncSetAttribute((const void*)vnet_kernel,
                        hipFuncAttributeMaxDynamicSharedMemorySize, LDS_BYTES);

    hipLaunchKernelGGL(prep_kernel, dim3((PREP_TOTAL + 255) / 256), dim3(256),
                       0, stream,
                       w1a, w1b, wa0, wa1, w2a, w2b, w3a, w3b, w3c, wa2,
                       b1a, b1b, ba0, ba1, b2a, b2b, b3a, b3b, b3c, wsh);

    const int B = 16384;
    hipLaunchKernelGGL(vnet_kernel, dim3(B / GB), dim3(NT), LDS_BYTES, stream,
                       x, ba2, w3d, b3d, wsh, outp);
}